// Round 1
// baseline (197.001 us; speedup 1.0000x reference)
//
#include <hip/hip_runtime.h>

#define ROW_LEN 8192
#define TOPK 8
#define THREADS 256
#define VEC4_PER_THREAD 8                 // 8 float4 = 32 elems/thread
#define ELEMS_PER_THREAD (VEC4_PER_THREAD * 4)
#define CAND_CAP 512

__global__ __launch_bounds__(THREADS) void topk_rows_kernel(
        const float* __restrict__ x,
        float* __restrict__ out_vals,     // [n_rows, 8] float
        float* __restrict__ out_idx,      // [n_rows, 8] indices stored as float
        int n_rows) {
    const int row = blockIdx.x;
    const int tid = threadIdx.x;
    if (row >= n_rows) return;

    const float4* rowp = (const float4*)(x + (size_t)row * ROW_LEN);

    __shared__ int   cnt;
    __shared__ float cand_v[CAND_CAP];
    __shared__ int   cand_i[CAND_CAP];
    if (tid == 0) cnt = 0;

    // ---- load 32 elements into registers, coalesced float4 ----
    float v[ELEMS_PER_THREAD];
#pragma unroll
    for (int k = 0; k < VEC4_PER_THREAD; k++) {
        float4 f = rowp[k * THREADS + tid];
        v[4 * k + 0] = f.x; v[4 * k + 1] = f.y;
        v[4 * k + 2] = f.z; v[4 * k + 3] = f.w;
    }

    // ---- per-thread max (31 fmax, compiler fuses to v_max3) ----
    float mx = v[0];
#pragma unroll
    for (int e = 1; e < ELEMS_PER_THREAD; e++) mx = fmaxf(mx, v[e]);

    // ---- conservative wave threshold in 6 shuffles (was 48):
    // Split wave into 8 groups of 8 lanes. T = min over groups of (group max
    // of lane maxima). The 8 group maxima are 8 distinct elements, each >= T,
    // so any element with val < T has >=8 distinct elements strictly above it
    // -> cannot be in the row's top-8. Hence collecting val >= T is a
    // superset of this wave's contribution to the top-8. T here is smaller
    // (more conservative) than the previous exact 8th-largest-lane-max, so
    // the candidate set only grows (~80/block expected; CAP=512 covers
    // overflow with probability < 1e-6 over all rows).
    float g = mx;
    g = fmaxf(g, __shfl_xor(g, 1, 64));
    g = fmaxf(g, __shfl_xor(g, 2, 64));
    g = fmaxf(g, __shfl_xor(g, 4, 64));   // group-of-8 max
    float T = g;
    T = fminf(T, __shfl_xor(T, 8, 64));
    T = fminf(T, __shfl_xor(T, 16, 64));
    T = fminf(T, __shfl_xor(T, 32, 64));  // min over the 8 group maxima

    __syncthreads();   // cnt initialized

    // ---- candidate collection: all register-resident values >= T ----
#pragma unroll
    for (int k = 0; k < VEC4_PER_THREAD; k++) {
#pragma unroll
        for (int j = 0; j < 4; j++) {
            float val = v[4 * k + j];
            if (val >= T) {
                int p = atomicAdd(&cnt, 1);
                if (p < CAND_CAP) {
                    cand_v[p] = val;
                    cand_i[p] = 4 * (k * THREADS + tid) + j;
                }
            }
        }
    }
    __syncthreads();

    // ---- parallel rank-select on wave 0: rank by (value desc, index asc).
    // Ranks are unique (index tiebreak) -> exactly 8 writers, race-free.
    if (tid < 64) {
        int n = cnt;
        if (n > CAND_CAP) n = CAND_CAP;
        for (int c = tid; c < n; c += 64) {
            float myv = cand_v[c];
            int   myi = cand_i[c];
            int rank = 0;
            for (int j = 0; j < n; j++) {
                float ov = cand_v[j];
                int   oi = cand_i[j];
                rank += (ov > myv) || (ov == myv && oi < myi);
            }
            if (rank < TOPK) {
                out_vals[(size_t)row * TOPK + rank] = myv;
                out_idx[(size_t)row * TOPK + rank]  = (float)myi;
            }
        }
    }
}

extern "C" void kernel_launch(void* const* d_in, const int* in_sizes, int n_in,
                              void* d_out, int out_size, void* d_ws, size_t ws_size,
                              hipStream_t stream) {
    const float* x = (const float*)d_in[0];
    float* out = (float*)d_out;
    const int n_rows = in_sizes[0] / ROW_LEN;          // 4096
    float* out_vals = out;                              // [n_rows*8] values
    float* out_idx  = out + (size_t)n_rows * TOPK;      // [n_rows*8] indices (as float)

    topk_rows_kernel<<<n_rows, THREADS, 0, stream>>>(x, out_vals, out_idx, n_rows);
}

// Round 2
// 186.558 us; speedup vs baseline: 1.0560x; 1.0560x over previous
//
#include <hip/hip_runtime.h>

#define ROW_LEN 8192
#define TOPK 8
#define THREADS 256
#define VEC4_PER_THREAD 8                 // 8 float4 = 32 elems/thread
#define ELEMS_PER_THREAD (VEC4_PER_THREAD * 4)
#define CAND_CAP 256
#define NGROUPS 32                        // 4 waves x 8 groups (8 lanes = 256 elems each)

__global__ __launch_bounds__(THREADS) void topk_rows_kernel(
        const float* __restrict__ x,
        float* __restrict__ out_vals,     // [n_rows, 8] float
        float* __restrict__ out_idx,      // [n_rows, 8] indices stored as float
        int n_rows) {
    const int row = blockIdx.x;
    const int tid = threadIdx.x;
    if (row >= n_rows) return;
    const int lane = tid & 63;
    const int wid  = tid >> 6;

    const float4* rowp = (const float4*)(x + (size_t)row * ROW_LEN);

    __shared__ int   cnt;
    __shared__ float gmax[NGROUPS];
    __shared__ float cand_v[CAND_CAP];
    __shared__ int   cand_i[CAND_CAP];
    if (tid == 0) cnt = 0;

    // ---- load 32 elements into registers, coalesced float4; keep per-float4 maxima ----
    float v[ELEMS_PER_THREAD];
    float m4[VEC4_PER_THREAD];
#pragma unroll
    for (int k = 0; k < VEC4_PER_THREAD; k++) {
        float4 f = rowp[k * THREADS + tid];
        v[4 * k + 0] = f.x; v[4 * k + 1] = f.y;
        v[4 * k + 2] = f.z; v[4 * k + 3] = f.w;
        m4[k] = fmaxf(fmaxf(f.x, f.y), fmaxf(f.z, f.w));
    }
    float mx = m4[0];
#pragma unroll
    for (int k = 1; k < VEC4_PER_THREAD; k++) mx = fmaxf(mx, m4[k]);

    // ---- per-wave group-of-8-lanes maxima (256 elems each), 3 shuffles ----
    float g = mx;
    g = fmaxf(g, __shfl_xor(g, 1, 64));
    g = fmaxf(g, __shfl_xor(g, 2, 64));
    g = fmaxf(g, __shfl_xor(g, 4, 64));
    if ((lane & 7) == 0) gmax[wid * 8 + (lane >> 3)] = g;

    __syncthreads();   // gmax complete, cnt initialized

    // ---- T = 8th largest of the 32 group maxima (value desc, index asc).
    // Exactly 8 distinct elements (the top-8 group maxima) are >= T, so any
    // element < T has >=8 elements above it -> cannot be in the row's top-8.
    // Those 8 maxima are themselves collected, so >=8 candidates always exist.
    // For Gaussian rows T ~ 3.05 sigma -> ~9 candidates/block (tail phases tiny).
    // Rank-count is wave-parallel over LDS broadcast reads (no serial shuffle chain);
    // each wave computes it redundantly (no extra barrier/broadcast needed).
    float myv = (lane < NGROUPS) ? gmax[lane] : -INFINITY;
    int rank = 0;
#pragma unroll
    for (int j = 0; j < NGROUPS; j++) {
        float o = gmax[j];
        rank += (o > myv) || (o == myv && j < lane);   // unique ranks via index tiebreak
    }
    unsigned long long bm = __ballot(rank == (TOPK - 1));  // exactly one lane (<32) matches
    float T = __shfl(myv, (int)__ffsll((unsigned long long)bm) - 1, 64);

    // ---- candidate collection: values >= T; per-float4 guard skips most bodies ----
#pragma unroll
    for (int k = 0; k < VEC4_PER_THREAD; k++) {
        if (m4[k] >= T) {
#pragma unroll
            for (int j = 0; j < 4; j++) {
                float val = v[4 * k + j];
                if (val >= T) {
                    int p = atomicAdd(&cnt, 1);
                    if (p < CAND_CAP) {
                        cand_v[p] = val;
                        cand_i[p] = 4 * (k * THREADS + tid) + j;
                    }
                }
            }
        }
    }
    __syncthreads();

    // ---- parallel rank-select on wave 0: rank by (value desc, index asc).
    // Ranks are unique (index tiebreak) -> exactly 8 writers, race-free. n ~ 9.
    if (tid < 64) {
        int n = cnt;
        if (n > CAND_CAP) n = CAND_CAP;
        for (int c = tid; c < n; c += 64) {
            float cv = cand_v[c];
            int   ci = cand_i[c];
            int r = 0;
            for (int j = 0; j < n; j++) {
                float ov = cand_v[j];
                int   oi = cand_i[j];
                r += (ov > cv) || (ov == cv && oi < ci);
            }
            if (r < TOPK) {
                out_vals[(size_t)row * TOPK + r] = cv;
                out_idx[(size_t)row * TOPK + r]  = (float)ci;
            }
        }
    }
}

extern "C" void kernel_launch(void* const* d_in, const int* in_sizes, int n_in,
                              void* d_out, int out_size, void* d_ws, size_t ws_size,
                              hipStream_t stream) {
    const float* x = (const float*)d_in[0];
    float* out = (float*)d_out;
    const int n_rows = in_sizes[0] / ROW_LEN;          // 4096
    float* out_vals = out;                              // [n_rows*8] values
    float* out_idx  = out + (size_t)n_rows * TOPK;      // [n_rows*8] indices (as float)

    topk_rows_kernel<<<n_rows, THREADS, 0, stream>>>(x, out_vals, out_idx, n_rows);
}